// Round 6
// baseline (110.384 us; speedup 1.0000x reference)
//
#include <hip/hip_runtime.h>

// CapsuleLayer dynamic routing, MI355X. fp32 in/out.
// C=10, B=128, N=1152, IN=8, OUT=16, 3 routing iters.
//
// v4 (round 6): G=2 + __launch_bounds__(384, 2).
//   History: G=2 @ default heuristic (r4) -> allocator capped at 128 VGPR
//   (4 waves/SIMD target) and spilled ~5 floats/thread to scratch-in-HBM
//   -> 59 us. G=1 (r5) -> 52 VGPR, clean, but every (c,b) block streams all
//   589 KB of W[c]: ~755 MB of L2 traffic (~22 us/XCD floor) + latency badly
//   hidden with only 52 VGPRs -> 53 us, VALUBusy 17%.
//   Fix: min-waves/EU=2 raises the VGPR budget to 256 -> G=2's 120-float
//   state allocates spill-free (~150 VGPR, 3 waves/SIMD). W register reuse
//   across the b-pair halves L2 traffic; all 640 blocks co-resident
//   (<= 3 blocks/CU x 256 CU); bigger budget lets the compiler keep many
//   more W loads in flight during the prior build.
//
// Layout: lane l: o-quad q = l&3 (owns o = q*4..q*4+3), row-sub r = l>>2.
//   Wave w covers rows [w*192,(w+1)*192) in 12 passes of 16 rows.
//   W float4 load = 16 rows x 64 B fully-consumed lines (coalescing minimum).
// Routing: logits scalar per (c,b,n) (reference keepdims broadcast).
//   Unnormalized softmax (|logit| <~ 30, fp32-safe). Quad dot via
//   __shfl_xor 1,2; wave reduce 4..32; cross-wave via ~1 KB LDS.

constexpr int C = 10, B = 128, N = 1152, IN = 8, OUT = 16;
constexpr int THREADS = 384;
constexpr int NW = THREADS / 64;          // 6 waves
constexpr int G = 2;                      // batches per block
constexpr int PASSES = N / (NW * 16);     // 12

__global__ __launch_bounds__(THREADS, 2)
void caps_route(const float* __restrict__ Xf, const float* __restrict__ Wf,
                float* __restrict__ Of) {
    __shared__ float lds_s[G][NW][OUT];   // per-wave weighted sums
    __shared__ float lds_sum[G][NW];      // per-wave softmax denominators
    __shared__ float lds_out[G][OUT];     // squashed outputs

    const int t = threadIdx.x;
    const int l = t & 63;
    const int wid = t >> 6;
    const int q = l & 3;        // o-quad: owns o = q*4 .. q*4+3
    const int rsub = l >> 2;    // row-sub within a pass (0..15)
    const int blk = blockIdx.x;
    const int c = blk >> 6;     // 64 consecutive blocks share c -> W[c] in L2
    const int b0 = (blk & 63) * G;

    float P[G][PASSES][4];

    // ---- priors: P[n][o] = sum_i x[b,n,i] * W[c,n,i,o] ----
    #pragma unroll
    for (int p = 0; p < PASSES; ++p) {
        const int n = wid * (16 * PASSES) + p * 16 + rsub;
        const float4* wr = (const float4*)(Wf + (size_t)(c * N + n) * (IN * OUT));
        float4 wv[IN];
        #pragma unroll
        for (int i = 0; i < IN; ++i) wv[i] = wr[i * 4 + q];   // 16 full lines/instr
        #pragma unroll
        for (int g = 0; g < G; ++g) {
            const float* xb = Xf + ((size_t)((b0 + g) * N + n)) * IN;
            const float4 xa = ((const float4*)xb)[0];
            const float4 xc = ((const float4*)xb)[1];
            const float xs[8] = { xa.x, xa.y, xa.z, xa.w, xc.x, xc.y, xc.z, xc.w };
            float a0 = 0.f, a1 = 0.f, a2 = 0.f, a3 = 0.f;
            #pragma unroll
            for (int i = 0; i < IN; ++i) {
                a0 = fmaf(xs[i], wv[i].x, a0);
                a1 = fmaf(xs[i], wv[i].y, a1);
                a2 = fmaf(xs[i], wv[i].z, a2);
                a3 = fmaf(xs[i], wv[i].w, a3);
            }
            P[g][p][0] = a0; P[g][p][1] = a1; P[g][p][2] = a2; P[g][p][3] = a3;
        }
    }

    // ---- dynamic routing ----
    float logit[G][PASSES];
    #pragma unroll
    for (int g = 0; g < G; ++g)
        #pragma unroll
        for (int p = 0; p < PASSES; ++p) logit[g][p] = 0.f;

    for (int it = 0; it < 3; ++it) {
        float s4[G][4];
        float ssum[G];
        #pragma unroll
        for (int g = 0; g < G; ++g) {
            ssum[g] = 0.f;
            #pragma unroll
            for (int k = 0; k < 4; ++k) s4[g][k] = 0.f;
        }
        #pragma unroll
        for (int g = 0; g < G; ++g) {
            #pragma unroll
            for (int p = 0; p < PASSES; ++p) {
                const float e = __expf(logit[g][p]);   // replicated across quad
                ssum[g] += e;
                #pragma unroll
                for (int k = 0; k < 4; ++k) s4[g][k] = fmaf(e, P[g][p][k], s4[g][k]);
            }
        }
        // reduce across the 16 row-subs of the wave (masks 4..32; quad bits
        // 0,1 carry replicas (ssum) / distinct o (s4) -> not summed)
        #pragma unroll
        for (int m = 4; m < 64; m <<= 1) {
            #pragma unroll
            for (int g = 0; g < G; ++g) {
                ssum[g] += __shfl_xor(ssum[g], m, 64);
                #pragma unroll
                for (int k = 0; k < 4; ++k) s4[g][k] += __shfl_xor(s4[g][k], m, 64);
            }
        }
        if (l < 4) {  // lane l == quad q: owns o = l*4..l*4+3
            #pragma unroll
            for (int g = 0; g < G; ++g)
                #pragma unroll
                for (int k = 0; k < 4; ++k) lds_s[g][wid][l * 4 + k] = s4[g][k];
        }
        if (l == 0) {
            #pragma unroll
            for (int g = 0; g < G; ++g) lds_sum[g][wid] = ssum[g];
        }
        __syncthreads();   // A

        // cross-wave combine + squash on t<32 (16-lane group per g)
        if (t < 32) {
            const int g = t >> 4, o = t & 15;
            float so = 0.f, S = 0.f;
            #pragma unroll
            for (int w = 0; w < NW; ++w) { so += lds_s[g][w][o]; S += lds_sum[g][w]; }
            so /= S;                          // s_o = softmax-weighted prior sum
            float r = so * so;                // ||s||^2 via 16-lane butterfly
            r += __shfl_xor(r, 1, 64);
            r += __shfl_xor(r, 2, 64);
            r += __shfl_xor(r, 4, 64);
            r += __shfl_xor(r, 8, 64);
            const float ov = so * (r / ((1.f + r) * sqrtf(r + 1e-8f)));
            if (it == 2) Of[((size_t)c * B + b0 + g) * OUT + o] = ov;
            else         lds_out[g][o] = ov;
        }

        if (it < 2) {
            __syncthreads();   // B
            float o4[G][4];
            #pragma unroll
            for (int g = 0; g < G; ++g)
                #pragma unroll
                for (int k = 0; k < 4; ++k) o4[g][k] = lds_out[g][q * 4 + k];
            // logit update: delta[n] = dot(out, P[n,:]) -> quad butterfly
            #pragma unroll
            for (int g = 0; g < G; ++g) {
                #pragma unroll
                for (int p = 0; p < PASSES; ++p) {
                    float d = o4[g][0] * P[g][p][0];
                    d = fmaf(o4[g][1], P[g][p][1], d);
                    d = fmaf(o4[g][2], P[g][p][2], d);
                    d = fmaf(o4[g][3], P[g][p][3], d);
                    d += __shfl_xor(d, 1, 64);
                    d += __shfl_xor(d, 2, 64);
                    logit[g][p] += d;
                }
            }
        }
    }
}

extern "C" void kernel_launch(void* const* d_in, const int* in_sizes, int n_in,
                              void* d_out, int out_size, void* d_ws, size_t ws_size,
                              hipStream_t stream) {
    const float* X = (const float*)d_in[0];   // [B,N,IN] fp32
    const float* W = (const float*)d_in[1];   // [C,N,IN,OUT] fp32
    float* O = (float*)d_out;                 // [C,B,OUT] fp32
    hipLaunchKernelGGL(caps_route, dim3(C * (B / G)), dim3(THREADS), 0, stream, X, W, O);
}

// Round 7
// 99.747 us; speedup vs baseline: 1.1066x; 1.1066x over previous
//
#include <hip/hip_runtime.h>

// CapsuleLayer dynamic routing, MI355X. fp32 in/out.
// C=10, B=128, N=1152, IN=8, OUT=16, 3 routing iters.
//
// v5 (round 7): G=2, THREADS=512, logit elimination.
//   Allocator empirics (r3/r4/r6): it will NOT exceed 128 VGPR for this
//   kernel regardless of __launch_bounds__ hints — it prefers 128+spill
//   (spill -> scratch-in-HBM -> 5.3 MB WRITE_SIZE, 59-69 us). So the state
//   must FIT under 128. Two changes:
//   (1) logit[G][P] (24 regs) eliminated: logit_k = dot(sum_{j<k} out_j, P)
//       because delta_j = dot(out_j, P). Carry only the accumulated output
//       quad-slice oa[G][4] (8 regs) and recompute the logit per iteration
//       (4 FMA + 2 quad shuffles/pass — exactly what the old separate
//       logit-update phase cost; that phase is deleted). Identical math.
//   (2) THREADS=512 (8 waves): PASSES=9, P[2][9][4]=72 floats. State ~100.
//       2 blocks/CU co-resident = 16 waves/CU (vs 12 at 384 threads).
//   W registers serve both batches (halves L2 W-traffic: ~400 MB -> ~12 us
//   floor; TA ~10 us; VALU ~9 us).
//
// Layout: lane l: o-quad q = l&3 (owns o = q*4..q*4+3), row-sub r = l>>2.
//   Wave w covers rows [w*144,(w+1)*144) in 9 passes of 16 rows.
//   W float4 load = 16 rows x 64 B fully-consumed lines (coalescing minimum;
//   the r2 row-per-lane layout hit 64 lines/instr = 137 us).
// Routing: logits scalar per (c,b,n) (reference keepdims broadcast).
//   Unnormalized softmax (|logit| <~ 30, fp32-safe). Quad dot via
//   __shfl_xor 1,2; wave reduce 4..32; cross-wave via ~1 KB LDS.

constexpr int C = 10, B = 128, N = 1152, IN = 8, OUT = 16;
constexpr int THREADS = 512;
constexpr int NW = THREADS / 64;          // 8 waves
constexpr int G = 2;                      // batches per block
constexpr int PASSES = N / (NW * 16);     // 9

__global__ __launch_bounds__(THREADS)
void caps_route(const float* __restrict__ Xf, const float* __restrict__ Wf,
                float* __restrict__ Of) {
    __shared__ float lds_s[G][NW][OUT];   // per-wave weighted sums
    __shared__ float lds_sum[G][NW];      // per-wave softmax denominators
    __shared__ float lds_out[G][OUT];     // squashed outputs (per iter)

    const int t = threadIdx.x;
    const int l = t & 63;
    const int wid = t >> 6;
    const int q = l & 3;        // o-quad: owns o = q*4 .. q*4+3
    const int rsub = l >> 2;    // row-sub within a pass (0..15)
    const int blk = blockIdx.x;
    const int c = blk >> 6;     // 64 consecutive blocks share c -> W[c] in L2
    const int b0 = (blk & 63) * G;

    float P[G][PASSES][4];

    // ---- priors: P[n][o] = sum_i x[b,n,i] * W[c,n,i,o] ----
    #pragma unroll
    for (int p = 0; p < PASSES; ++p) {
        const int n = wid * (16 * PASSES) + p * 16 + rsub;
        const float4* wr = (const float4*)(Wf + (size_t)(c * N + n) * (IN * OUT));
        float4 wv[IN];
        #pragma unroll
        for (int i = 0; i < IN; ++i) wv[i] = wr[i * 4 + q];   // 16 full lines/instr
        #pragma unroll
        for (int g = 0; g < G; ++g) {
            const float4* xr = (const float4*)(Xf + (size_t)((b0 + g) * N + n) * IN);
            const float4 xa = xr[0], xc = xr[1];
            const float xs[8] = { xa.x, xa.y, xa.z, xa.w, xc.x, xc.y, xc.z, xc.w };
            float a0 = 0.f, a1 = 0.f, a2 = 0.f, a3 = 0.f;
            #pragma unroll
            for (int i = 0; i < IN; ++i) {
                a0 = fmaf(xs[i], wv[i].x, a0);
                a1 = fmaf(xs[i], wv[i].y, a1);
                a2 = fmaf(xs[i], wv[i].z, a2);
                a3 = fmaf(xs[i], wv[i].w, a3);
            }
            P[g][p][0] = a0; P[g][p][1] = a1; P[g][p][2] = a2; P[g][p][3] = a3;
        }
    }

    // accumulated output quad-slice; logit[p] == dot(oa_full16, P_full16[p])
    float oa[G][4];
    #pragma unroll
    for (int g = 0; g < G; ++g)
        #pragma unroll
        for (int k = 0; k < 4; ++k) oa[g][k] = 0.f;

    // ---- dynamic routing ----
    for (int it = 0; it < 3; ++it) {
        float s4[G][4];
        float ssum[G];
        if (it == 0) {
            // logits are all 0 -> e = 1: plain sums
            #pragma unroll
            for (int g = 0; g < G; ++g) {
                ssum[g] = (float)PASSES;
                #pragma unroll
                for (int k = 0; k < 4; ++k) {
                    float a = 0.f;
                    #pragma unroll
                    for (int p = 0; p < PASSES; ++p) a += P[g][p][k];
                    s4[g][k] = a;
                }
            }
        } else {
            #pragma unroll
            for (int g = 0; g < G; ++g) {
                ssum[g] = 0.f;
                #pragma unroll
                for (int k = 0; k < 4; ++k) s4[g][k] = 0.f;
                #pragma unroll
                for (int p = 0; p < PASSES; ++p) {
                    // logit[p] = dot(out_accum, P[p]) via quad butterfly
                    float d = oa[g][0] * P[g][p][0];
                    d = fmaf(oa[g][1], P[g][p][1], d);
                    d = fmaf(oa[g][2], P[g][p][2], d);
                    d = fmaf(oa[g][3], P[g][p][3], d);
                    d += __shfl_xor(d, 1, 64);
                    d += __shfl_xor(d, 2, 64);
                    const float e = __expf(d);      // replicated across quad
                    ssum[g] += e;
                    #pragma unroll
                    for (int k = 0; k < 4; ++k) s4[g][k] = fmaf(e, P[g][p][k], s4[g][k]);
                }
            }
        }
        // reduce across the 16 row-subs of the wave (masks 4..32; quad bits
        // 0,1 carry replicas (ssum) / distinct o (s4) -> not summed)
        #pragma unroll
        for (int m = 4; m < 64; m <<= 1) {
            #pragma unroll
            for (int g = 0; g < G; ++g) {
                ssum[g] += __shfl_xor(ssum[g], m, 64);
                #pragma unroll
                for (int k = 0; k < 4; ++k) s4[g][k] += __shfl_xor(s4[g][k], m, 64);
            }
        }
        if (l < 4) {  // lane l == quad q: owns o = l*4..l*4+3
            #pragma unroll
            for (int g = 0; g < G; ++g)
                #pragma unroll
                for (int k = 0; k < 4; ++k) lds_s[g][wid][l * 4 + k] = s4[g][k];
        }
        if (l == 0) {
            #pragma unroll
            for (int g = 0; g < G; ++g) lds_sum[g][wid] = ssum[g];
        }
        __syncthreads();   // A

        // cross-wave combine + squash on t<32 (16-lane group per g)
        if (t < 32) {
            const int g = t >> 4, o = t & 15;
            float so = 0.f, S = 0.f;
            #pragma unroll
            for (int w = 0; w < NW; ++w) { so += lds_s[g][w][o]; S += lds_sum[g][w]; }
            so /= S;                          // s_o = softmax-weighted prior sum
            float r = so * so;                // ||s||^2 via 16-lane butterfly
            r += __shfl_xor(r, 1, 64);
            r += __shfl_xor(r, 2, 64);
            r += __shfl_xor(r, 4, 64);
            r += __shfl_xor(r, 8, 64);
            const float ov = so * (r / ((1.f + r) * sqrtf(r + 1e-8f)));
            if (it == 2) Of[((size_t)c * B + b0 + g) * OUT + o] = ov;
            else         lds_out[g][o] = ov;
        }

        if (it < 2) {
            __syncthreads();   // B
            #pragma unroll
            for (int g = 0; g < G; ++g)
                #pragma unroll
                for (int k = 0; k < 4; ++k) oa[g][k] += lds_out[g][q * 4 + k];
        }
    }
}

extern "C" void kernel_launch(void* const* d_in, const int* in_sizes, int n_in,
                              void* d_out, int out_size, void* d_ws, size_t ws_size,
                              hipStream_t stream) {
    const float* X = (const float*)d_in[0];   // [B,N,IN] fp32
    const float* W = (const float*)d_in[1];   // [C,N,IN,OUT] fp32
    float* O = (float*)d_out;                 // [C,B,OUT] fp32
    hipLaunchKernelGGL(caps_route, dim3(C * (B / G)), dim3(THREADS), 0, stream, X, W, O);
}